// Round 10
// baseline (174.804 us; speedup 1.0000x reference)
//
#include <hip/hip_runtime.h>
#include <hip/hip_fp16.h>

#define NODES 100000
#define EDGES 1600000

#define BSHIFT 9
#define BNODES 512                                   // nodes per bucket
#define NBUCK ((NODES + BNODES - 1) / BNODES)        // 196
#define BCAP 10240                                   // max edges per bucket (avg 8163)

#define PREP_BLKS 6                                  // 4 (W1) + 2 (W2)
#define SC 1563                                      // scatter blocks (1024 edges each)
#define BUILD_BLKS NBUCK                             // 196
#define GB 782                                       // gemm1 blocks (128 rows each)

typedef __attribute__((ext_vector_type(8))) short short8;
typedef __attribute__((ext_vector_type(8))) _Float16 half8;
typedef __attribute__((ext_vector_type(4))) float f32x4;

// ---------------------------------------------------------------------------
// bf16 / fp16 helpers
// ---------------------------------------------------------------------------
__device__ inline unsigned short f2bf(float f) {
    unsigned u = __builtin_bit_cast(unsigned, f);
    u = u + 0x7fff + ((u >> 16) & 1);
    return (unsigned short)(u >> 16);
}
__device__ inline float bf2f(unsigned short h) {
    unsigned u = ((unsigned)h) << 16;
    return __builtin_bit_cast(float, u);
}
__device__ inline unsigned short f2h_bits(float f) {
    __half h = __float2half_rn(f);
    return __builtin_bit_cast(unsigned short, h);
}
__device__ inline float h2f(unsigned short bits) {
    return __half2float(__builtin_bit_cast(__half, bits));
}
__device__ inline float2 h2f2(unsigned int bits) {
    __half2 h = __builtin_bit_cast(__half2, bits);
    return __half22float2(h);
}

// ---------------------------------------------------------------------------
// KERNEL A: prep (blocks 0..5) || bucket_scatter (blocks 6..6+SC)
//   prep: W1 -> hi/lo bf16 frags; W2 -> fp16 frags
//   frag layout (16x16x32): k = kt*32 + (lane>>4)*8 + i, c = ct*16 + (lane&15)
//   scatter: multisplit edges into NBUCK node-range buckets (dense writes)
// ---------------------------------------------------------------------------

__global__ __launch_bounds__(512) void prep_scatter(const float* __restrict__ W1,
                                                    const float* __restrict__ W2,
                                                    unsigned short* __restrict__ wh1,
                                                    unsigned short* __restrict__ wl1,
                                                    unsigned short* __restrict__ w2f,
                                                    const int* __restrict__ erow,
                                                    const int* __restrict__ ecol,
                                                    int* __restrict__ gcur,
                                                    int2* __restrict__ temp) {
    const int tid = threadIdx.x;
    const int b = blockIdx.x;

    if (b < 4) {
        // W1 hi/lo bf16 frags (2048 frags total, 512/block)
        constexpr int NCT = 8;  // 128/16
        int idx = b * 512 + tid;
        int lane = idx & 63;
        int rem = idx >> 6;
        int ct = rem % NCT;
        int kt = rem / NCT;
        int kbase = kt * 32 + ((lane >> 4) * 8);
        int c = ct * 16 + (lane & 15);
#pragma unroll
        for (int i = 0; i < 8; i++) {
            float v = W1[(size_t)(kbase + i) * 128 + c];
            unsigned short hi = f2bf(v);
            unsigned short lo = f2bf(v - bf2f(hi));
            wh1[(size_t)idx * 8 + i] = hi;
            wl1[(size_t)idx * 8 + i] = lo;
        }
    } else if (b < PREP_BLKS) {
        // W2 fp16 frags (1024 frags total, 512/block)
        constexpr int NCT = 4;  // 64/16
        int idx = (b - 4) * 512 + tid;
        int lane = idx & 63;
        int rem = idx >> 6;
        int ct = rem % NCT;
        int kt = rem / NCT;
        int kbase = kt * 32 + ((lane >> 4) * 8);
        int c = ct * 16 + (lane & 15);
#pragma unroll
        for (int i = 0; i < 8; i++) {
            w2f[(size_t)idx * 8 + i] = f2h_bits(W2[(size_t)(kbase + i) * 64 + c]);
        }
    } else {
        __shared__ int hist[NBUCK];
        __shared__ int rbase[NBUCK];
        const int ebase = (b - PREP_BLKS) * 1024;
        if (tid < NBUCK) hist[tid] = 0;
        __syncthreads();

        const int e0 = ebase + tid;
        const int e1 = ebase + tid + 512;
        const bool v0 = e0 < EDGES;
        const bool v1 = e1 < EDGES;
        int c0 = 0, s0 = 0, b0 = 0, r0 = 0;
        int c1 = 0, s1 = 0, b1 = 0, r1 = 0;
        if (v0) {
            c0 = ecol[e0]; s0 = erow[e0];
            b0 = c0 >> BSHIFT;
            r0 = atomicAdd(&hist[b0], 1);
        }
        if (v1) {
            c1 = ecol[e1]; s1 = erow[e1];
            b1 = c1 >> BSHIFT;
            r1 = atomicAdd(&hist[b1], 1);
        }
        __syncthreads();
        if (tid < NBUCK) {
            int h = hist[tid];
            rbase[tid] = h ? atomicAdd(&gcur[tid], h) : 0;
        }
        __syncthreads();
        if (v0) {
            int2 v; v.x = s0; v.y = c0 & (BNODES - 1);
            temp[(size_t)b0 * BCAP + rbase[b0] + r0] = v;
        }
        if (v1) {
            int2 v; v.x = s1; v.y = c1 & (BNODES - 1);
            temp[(size_t)b1 * BCAP + rbase[b1] + r1] = v;
        }
    }
}

// ---------------------------------------------------------------------------
// GEMM1 body via MFMA 16x16x32 bf16, split-precision: H = X @ W1 (fp16 out)
// ---------------------------------------------------------------------------

__device__ __forceinline__ void gemm1_body(const float* __restrict__ X,
                                           const unsigned short* __restrict__ wh,
                                           const unsigned short* __restrict__ wl,
                                           unsigned short* __restrict__ H,
                                           unsigned short* s_wh,
                                           unsigned short* s_wl,
                                           int tid, int bid) {
    constexpr int NCT = 8;

    const int wave = tid >> 6;
    const int lane = tid & 63;

    const int row0 = bid * 128 + wave * 16 + (lane & 15);
    const bool active = (bid * 128 + wave * 16) < NODES;  // wave-uniform

    float xs[4][8];
    if (active) {
        const float* xrow = X + (size_t)row0 * 128 + ((lane >> 4) * 8);
#pragma unroll
        for (int kt = 0; kt < 4; kt++) {
            float4 a = *(const float4*)(xrow + kt * 32);
            float4 b = *(const float4*)(xrow + kt * 32 + 4);
            xs[kt][0] = a.x; xs[kt][1] = a.y; xs[kt][2] = a.z; xs[kt][3] = a.w;
            xs[kt][4] = b.x; xs[kt][5] = b.y; xs[kt][6] = b.z; xs[kt][7] = b.w;
        }
    }

#pragma unroll
    for (int j = 0; j < 4; j++) {
        __builtin_amdgcn_global_load_lds((const unsigned int*)((const char*)wh + ((size_t)tid + j * 512) * 16),
                                         (unsigned int*)(s_wh + ((size_t)tid + j * 512) * 8), 16, 0, 0);
        __builtin_amdgcn_global_load_lds((const unsigned int*)((const char*)wl + ((size_t)tid + j * 512) * 16),
                                         (unsigned int*)(s_wl + ((size_t)tid + j * 512) * 8), 16, 0, 0);
    }
    __syncthreads();

    if (!active) return;

    short8 ah[4], al[4];
#pragma unroll
    for (int kt = 0; kt < 4; kt++) {
#pragma unroll
        for (int i = 0; i < 8; i++) {
            unsigned short hi = f2bf(xs[kt][i]);
            unsigned short lo = f2bf(xs[kt][i] - bf2f(hi));
            ah[kt][i] = (short)hi;
            al[kt][i] = (short)lo;
        }
    }

    f32x4 acc[NCT];
#pragma unroll
    for (int ct = 0; ct < NCT; ct++) acc[ct] = (f32x4){0.f, 0.f, 0.f, 0.f};

#pragma unroll
    for (int kt = 0; kt < 4; kt++) {
#pragma unroll
        for (int ct = 0; ct < NCT; ct++) {
            const int fo = ((kt * NCT + ct) * 64 + lane) * 8;
            short8 bh = *(const short8*)&s_wh[fo];
            short8 bl = *(const short8*)&s_wl[fo];
            acc[ct] = __builtin_amdgcn_mfma_f32_16x16x32_bf16(ah[kt], bh, acc[ct], 0, 0, 0);
            acc[ct] = __builtin_amdgcn_mfma_f32_16x16x32_bf16(al[kt], bh, acc[ct], 0, 0, 0);
            acc[ct] = __builtin_amdgcn_mfma_f32_16x16x32_bf16(ah[kt], bl, acc[ct], 0, 0, 0);
        }
    }

    // D layout: col = lane&15, row = (lane>>4)*4 + reg
    const int rbase = bid * 128 + wave * 16 + ((lane >> 4) * 4);
#pragma unroll
    for (int ct = 0; ct < NCT; ct++) {
#pragma unroll
        for (int r = 0; r < 4; r++) {
            H[(size_t)(rbase + r) * 128 + ct * 16 + (lane & 15)] = f2h_bits(acc[ct][r]);
        }
    }
}

// ---------------------------------------------------------------------------
// KERNEL B: bucket_build (blocks 0..195, 512 threads) || gemm1 (blocks 196..)
// build placed FIRST: its latency-bound LDS scans co-reside with gemm1's
// memory/MFMA blocks on the same CUs.
// ---------------------------------------------------------------------------

__global__ __launch_bounds__(512) void gemm1_build(const float* __restrict__ X,
                                                   const unsigned short* __restrict__ wh,
                                                   const unsigned short* __restrict__ wl,
                                                   unsigned short* __restrict__ H,
                                                   const int2* __restrict__ temp,
                                                   const int* __restrict__ gcur,
                                                   int* __restrict__ row_start,
                                                   float* __restrict__ dis,
                                                   int* __restrict__ esrc) {
    __shared__ __align__(16) char smem[65536];  // union: gemm W tiles / build arrays
    const int tid = threadIdx.x;

    if (blockIdx.x >= BUILD_BLKS) {
        unsigned short* s_wh = (unsigned short*)smem;
        unsigned short* s_wl = s_wh + 2048 * 8;
        gemm1_body(X, wh, wl, H, s_wh, s_wl, tid, blockIdx.x - BUILD_BLKS);
        return;
    }

    // ---- bucket_build, 512 threads ----
    int* cnt = (int*)smem;              // [512]
    int* offs = cnt + BNODES;           // [512]
    int* cur = offs + BNODES;           // [512]
    int* ssc = cur + BNODES;            // [256]
    const int b = blockIdx.x;

    // inclusive scan of bucket sizes (196 ints)
    if (tid < 256) ssc[tid] = (tid < NBUCK) ? gcur[tid] : 0;
    __syncthreads();
    for (int d = 1; d < 256; d <<= 1) {
        int x = (tid < 256 && tid >= d) ? ssc[tid - d] : 0;
        __syncthreads();
        if (tid < 256) ssc[tid] += x;
        __syncthreads();
    }
    const int size = gcur[b];
    const int gbase = ssc[b] - size;  // exclusive prefix
    if (b == 0 && tid == 0) row_start[NODES] = EDGES;

    cnt[tid] = 0;
    __syncthreads();

    for (int i = tid; i < size; i += 512) {
        int2 v = temp[(size_t)b * BCAP + i];
        atomicAdd(&cnt[v.y], 1);
    }
    __syncthreads();

    offs[tid] = cnt[tid];
    __syncthreads();
    for (int d = 1; d < BNODES; d <<= 1) {
        int x = (tid >= d) ? offs[tid - d] : 0;
        __syncthreads();
        offs[tid] += x;
        __syncthreads();
    }
    {
        int excl = offs[tid] - cnt[tid];
        cur[tid] = excl;
        int v = b * BNODES + tid;
        if (v < NODES) {
            row_start[v] = gbase + excl;
            dis[v] = rsqrtf((float)(cnt[tid] + 1));  // +1 self-loop
        }
    }
    __syncthreads();

    for (int i = tid; i < size; i += 512) {
        int2 v = temp[(size_t)b * BCAP + i];
        int pos = gbase + atomicAdd(&cur[v.y], 1);
        esrc[pos] = v.x;
    }
}

// ---------------------------------------------------------------------------
// FUSED agg1 + gemm2:
//   phase A: out1[v] = relu(dv*(S dis_s*h1[s] + dv*h1[v]) + b1) -> f32 LDS
//   phase B: h2[v] = out1[v] @ W2 via MFMA f16 (W2 frags staged in LDS)
// 16 nodes/block, GL=16 lanes/node; exact grid 6250 (barrier-safe, no tail).
// ---------------------------------------------------------------------------

__global__ __launch_bounds__(256, 6) void agg1_gemm2(const unsigned short* __restrict__ H,
                                                     const int* __restrict__ row_start,
                                                     const int* __restrict__ edge_src,
                                                     const float* __restrict__ dis,
                                                     const float* __restrict__ b1,
                                                     const unsigned short* __restrict__ w2f,
                                                     unsigned short* __restrict__ H2) {
    __shared__ float h_lds[16][132];            // 8.25 KB (stride 132)
    __shared__ unsigned short s_w2[1024 * 8];   // 16 KB fp16 W2 frags

    const int tid = threadIdx.x;
    const int lane = tid & 63;
    const int sub = lane & 15;
    const int grp = lane >> 4;
    const int nl = (tid >> 6) * 4 + grp;        // node_local in [0,16)
    const int v = blockIdx.x * 16 + nl;

    // stage W2 frags (16KB, linear) — latency hides under the gather phase
#pragma unroll
    for (int j = 0; j < 4; j++) {
        __builtin_amdgcn_global_load_lds((const unsigned int*)((const char*)w2f + ((size_t)tid + j * 256) * 16),
                                         (unsigned int*)(s_w2 + ((size_t)tid + j * 256) * 8), 16, 0, 0);
    }

    // ---- phase A: dis-weighted gather ----
    const uint4* __restrict__ Hq = (const uint4*)H;
    const int e0 = row_start[v];
    const int e1 = row_start[v + 1];
    const float dv = dis[v];

    const float4 ba = ((const float4*)b1)[sub * 2];
    const float4 bb = ((const float4*)b1)[sub * 2 + 1];

    uint4 gs = Hq[(size_t)v * 16 + sub];  // self row

    int i0 = edge_src[min(e0 + 0, EDGES - 1)];
    int i1 = edge_src[min(e0 + 1, EDGES - 1)];
    int i2 = edge_src[min(e0 + 2, EDGES - 1)];
    int i3 = edge_src[min(e0 + 3, EDGES - 1)];
    float d0 = dis[i0], d1 = dis[i1], d2 = dis[i2], d3 = dis[i3];

    float a0, a1, a2, a3, a4, a5, a6, a7;
    {
        float2 f0 = h2f2(gs.x), f1 = h2f2(gs.y), f2 = h2f2(gs.z), f3 = h2f2(gs.w);
        a0 = f0.x * dv; a1 = f0.y * dv; a2 = f1.x * dv; a3 = f1.y * dv;
        a4 = f2.x * dv; a5 = f2.y * dv; a6 = f3.x * dv; a7 = f3.y * dv;
    }

    for (int k = e0; k < e1; k += 4) {
        uint4 g0 = Hq[(size_t)i0 * 16 + sub];
        uint4 g1 = Hq[(size_t)i1 * 16 + sub];
        uint4 g2 = Hq[(size_t)i2 * 16 + sub];
        uint4 g3 = Hq[(size_t)i3 * 16 + sub];
        const int n0 = edge_src[min(k + 4, EDGES - 1)];
        const int n1 = edge_src[min(k + 5, EDGES - 1)];
        const int n2 = edge_src[min(k + 6, EDGES - 1)];
        const int n3 = edge_src[min(k + 7, EDGES - 1)];
        const float dn0 = dis[n0], dn1 = dis[n1], dn2 = dis[n2], dn3 = dis[n3];
        const float w0 = d0;
        const float w1 = (k + 1 < e1) ? d1 : 0.f;
        const float w2 = (k + 2 < e1) ? d2 : 0.f;
        const float w3 = (k + 3 < e1) ? d3 : 0.f;
#define ACC(G, W)                                                        \
        {                                                                \
            float2 f0 = h2f2(G.x), f1 = h2f2(G.y);                       \
            float2 f2 = h2f2(G.z), f3 = h2f2(G.w);                       \
            a0 = fmaf(f0.x, W, a0); a1 = fmaf(f0.y, W, a1);              \
            a2 = fmaf(f1.x, W, a2); a3 = fmaf(f1.y, W, a3);              \
            a4 = fmaf(f2.x, W, a4); a5 = fmaf(f2.y, W, a5);              \
            a6 = fmaf(f3.x, W, a6); a7 = fmaf(f3.y, W, a7);              \
        }
        ACC(g0, w0)
        ACC(g1, w1)
        ACC(g2, w2)
        ACC(g3, w3)
#undef ACC
        i0 = n0; i1 = n1; i2 = n2; i3 = n3;
        d0 = dn0; d1 = dn1; d2 = dn2; d3 = dn3;
    }

    // out1 epilogue -> LDS (f32, full precision, relu'd)
    {
        float4 oa, ob;
        oa.x = fmaxf(fmaf(a0, dv, ba.x), 0.f);
        oa.y = fmaxf(fmaf(a1, dv, ba.y), 0.f);
        oa.z = fmaxf(fmaf(a2, dv, ba.z), 0.f);
        oa.w = fmaxf(fmaf(a3, dv, ba.w), 0.f);
        ob.x = fmaxf(fmaf(a4, dv, bb.x), 0.f);
        ob.y = fmaxf(fmaf(a5, dv, bb.y), 0.f);
        ob.z = fmaxf(fmaf(a6, dv, bb.z), 0.f);
        ob.w = fmaxf(fmaf(a7, dv, bb.w), 0.f);
        *(float4*)&h_lds[nl][sub * 8] = oa;
        *(float4*)&h_lds[nl][sub * 8 + 4] = ob;
    }
    __syncthreads();  // h_lds ready + W2 frags staged (vmcnt drained)

    // ---- phase B: MFMA f16 matvec, wave ct = wave id, 4 MFMA ----
    const int ct = tid >> 6;
    f32x4 acc = (f32x4){0.f, 0.f, 0.f, 0.f};
#pragma unroll
    for (int kt = 0; kt < 4; kt++) {
        const int arow = lane & 15;
        const int acol = (lane >> 4) * 8 + kt * 32;
        float4 pa = *(const float4*)&h_lds[arow][acol];
        float4 pb = *(const float4*)&h_lds[arow][acol + 4];
        half8 af;
        af[0] = (_Float16)pa.x; af[1] = (_Float16)pa.y;
        af[2] = (_Float16)pa.z; af[3] = (_Float16)pa.w;
        af[4] = (_Float16)pb.x; af[5] = (_Float16)pb.y;
        af[6] = (_Float16)pb.z; af[7] = (_Float16)pb.w;
        half8 bf = *(const half8*)&s_w2[((kt * 4 + ct) * 64 + lane) * 8];
        acc = __builtin_amdgcn_mfma_f32_16x16x32_f16(af, bf, acc, 0, 0, 0);
    }

    // D layout: col = lane&15 (out ch ct*16+col), row = (lane>>4)*4 + reg (node)
    const int rbase = blockIdx.x * 16 + ((lane >> 4) * 4);
#pragma unroll
    for (int r = 0; r < 4; r++) {
        H2[(size_t)(rbase + r) * 64 + ct * 16 + (lane & 15)] = f2h_bits(acc[r]);
    }
}

// ---------------------------------------------------------------------------
// Aggregation layer 2 (64ch fp16 in, f32 out), dis-weighted edges
// ---------------------------------------------------------------------------

__global__ __launch_bounds__(256, 8) void agg_l2(const unsigned short* __restrict__ H,
                                                 const int* __restrict__ row_start,
                                                 const int* __restrict__ edge_src,
                                                 const float* __restrict__ dis,
                                                 const float* __restrict__ bias,
                                                 float* __restrict__ OUT) {
    constexpr int RQ = 8;  // row length in uint4

    const int lane = threadIdx.x & 63;
    const int sub = lane & 7;
    const int grp = lane >> 3;
    const int wid = (blockIdx.x * 256 + threadIdx.x) >> 6;
    const int v = wid * 8 + grp;

    const uint4* __restrict__ Hq = (const uint4*)H;

    const int e0 = row_start[v];
    const int e1 = row_start[v + 1];
    const float dv = dis[v];

    const float4 ba = ((const float4*)bias)[sub * 2];
    const float4 bb = ((const float4*)bias)[sub * 2 + 1];

    uint4 gs = Hq[(size_t)v * RQ + sub];

    int i0 = edge_src[min(e0 + 0, EDGES - 1)];
    int i1 = edge_src[min(e0 + 1, EDGES - 1)];
    int i2 = edge_src[min(e0 + 2, EDGES - 1)];
    int i3 = edge_src[min(e0 + 3, EDGES - 1)];
    float d0 = dis[i0], d1 = dis[i1], d2 = dis[i2], d3 = dis[i3];

    float a0, a1, a2, a3, a4, a5, a6, a7;
    {
        float2 f0 = h2f2(gs.x), f1 = h2f2(gs.y), f2 = h2f2(gs.z), f3 = h2f2(gs.w);
        a0 = f0.x * dv; a1 = f0.y * dv; a2 = f1.x * dv; a3 = f1.y * dv;
        a4 = f2.x * dv; a5 = f2.y * dv; a6 = f3.x * dv; a7 = f3.y * dv;
    }

    for (int k = e0; k < e1; k += 4) {
        uint4 g0 = Hq[(size_t)i0 * RQ + sub];
        uint4 g1 = Hq[(size_t)i1 * RQ + sub];
        uint4 g2 = Hq[(size_t)i2 * RQ + sub];
        uint4 g3 = Hq[(size_t)i3 * RQ + sub];
        const int n0 = edge_src[min(k + 4, EDGES - 1)];
        const int n1 = edge_src[min(k + 5, EDGES - 1)];
        const int n2 = edge_src[min(k + 6, EDGES - 1)];
        const int n3 = edge_src[min(k + 7, EDGES - 1)];
        const float dn0 = dis[n0], dn1 = dis[n1], dn2 = dis[n2], dn3 = dis[n3];
        const float w0 = d0;
        const float w1 = (k + 1 < e1) ? d1 : 0.f;
        const float w2 = (k + 2 < e1) ? d2 : 0.f;
        const float w3 = (k + 3 < e1) ? d3 : 0.f;
#define ACC(G, W)                                                        \
        {                                                                \
            float2 f0 = h2f2(G.x), f1 = h2f2(G.y);                       \
            float2 f2 = h2f2(G.z), f3 = h2f2(G.w);                       \
            a0 = fmaf(f0.x, W, a0); a1 = fmaf(f0.y, W, a1);              \
            a2 = fmaf(f1.x, W, a2); a3 = fmaf(f1.y, W, a3);              \
            a4 = fmaf(f2.x, W, a4); a5 = fmaf(f2.y, W, a5);              \
            a6 = fmaf(f3.x, W, a6); a7 = fmaf(f3.y, W, a7);              \
        }
        ACC(g0, w0)
        ACC(g1, w1)
        ACC(g2, w2)
        ACC(g3, w3)
#undef ACC
        i0 = n0; i1 = n1; i2 = n2; i3 = n3;
        d0 = dn0; d1 = dn1; d2 = dn2; d3 = dn3;
    }

    float4 oa, ob;
    oa.x = fmaf(a0, dv, ba.x); oa.y = fmaf(a1, dv, ba.y);
    oa.z = fmaf(a2, dv, ba.z); oa.w = fmaf(a3, dv, ba.w);
    ob.x = fmaf(a4, dv, bb.x); ob.y = fmaf(a5, dv, bb.y);
    ob.z = fmaf(a6, dv, bb.z); ob.w = fmaf(a7, dv, bb.w);
    float* outp = OUT + (size_t)v * 64 + sub * 8;
    *(float4*)(outp) = oa;
    *(float4*)(outp + 4) = ob;
}

// ---------------------------------------------------------------------------

extern "C" void kernel_launch(void* const* d_in, const int* in_sizes, int n_in,
                              void* d_out, int out_size, void* d_ws, size_t ws_size,
                              hipStream_t stream) {
    const float* x   = (const float*)d_in[0];
    const int* eidx  = (const int*)d_in[1];
    const float* W1  = (const float*)d_in[2];
    const float* b1  = (const float*)d_in[3];
    const float* W2  = (const float*)d_in[4];
    const float* b2  = (const float*)d_in[5];
    float* out = (float*)d_out;

    const int* erow = eidx;          // sources
    const int* ecol = eidx + EDGES;  // targets

    // workspace carve-up (256B aligned)
    char* w = (char*)d_ws;
    size_t off = 0;
    auto alloc = [&](size_t bytes) -> void* {
        void* p = w + off;
        off += (bytes + 255) & ~(size_t)255;
        return p;
    };
    float* dis     = (float*)alloc((size_t)NODES * 4);
    int*   rowst   = (int*)alloc((size_t)(NODES + 1) * 4);
    int*   esrc    = (int*)alloc((size_t)EDGES * 4);
    int*   gcur    = (int*)alloc(NBUCK * 4);
    int2*  temp    = (int2*)alloc((size_t)NBUCK * BCAP * 8);
    unsigned short* wh1 = (unsigned short*)alloc(2048 * 8 * 2);
    unsigned short* wl1 = (unsigned short*)alloc(2048 * 8 * 2);
    unsigned short* w2f = (unsigned short*)alloc(1024 * 8 * 2);
    unsigned short* bufA = (unsigned short*)alloc((size_t)NODES * 128 * 2);  // h1 (fp16)
    unsigned short* bufC = (unsigned short*)alloc((size_t)NODES * 64 * 2);   // h2 (fp16)

    hipMemsetAsync(gcur, 0, NBUCK * 4, stream);

    // 1) prep (W frags) || edge multisplit
    prep_scatter<<<PREP_BLKS + SC, 512, 0, stream>>>(W1, W2, wh1, wl1, w2f,
                                                     erow, ecol, gcur, temp);

    // 2) bucket_build || gemm1 (h1 = x@W1, fp16)
    gemm1_build<<<BUILD_BLKS + GB, 512, 0, stream>>>(x, wh1, wl1, bufA,
                                                     temp, gcur, rowst, dis, esrc);

    // 3) FUSED agg1 + gemm2: h2 = relu(dis*(S dis_s h1) + b1) @ W2  (fp16)
    agg1_gemm2<<<NODES / 16, 256, 0, stream>>>(bufA, rowst, esrc, dis, b1, w2f, bufC);

    // 4) agg2: out = dis*(S dis_s h2 + dis_v h2[v]) + b2  (f32)
    agg_l2<<<NODES / 32, 256, 0, stream>>>(bufC, rowst, esrc, dis, b2, out);
}

// Round 11
// 167.339 us; speedup vs baseline: 1.0446x; 1.0446x over previous
//
#include <hip/hip_runtime.h>
#include <hip/hip_fp16.h>

#define NODES 100000
#define EDGES 1600000

#define BSHIFT 9
#define BNODES 512                                   // nodes per bucket
#define NBUCK ((NODES + BNODES - 1) / BNODES)        // 196
#define BCAP 10240                                   // max edges per bucket (avg 8163)

#define GB 782                                       // gemm1 blocks (128 rows each)
#define SC 1563                                      // scatter blocks (1024 edges each)

typedef __attribute__((ext_vector_type(8))) short short8;
typedef __attribute__((ext_vector_type(8))) _Float16 half8;
typedef __attribute__((ext_vector_type(4))) float f32x4;

// ---------------------------------------------------------------------------
// bf16 / fp16 helpers
// ---------------------------------------------------------------------------
__device__ inline unsigned short f2bf(float f) {
    unsigned u = __builtin_bit_cast(unsigned, f);
    u = u + 0x7fff + ((u >> 16) & 1);
    return (unsigned short)(u >> 16);
}
__device__ inline float bf2f(unsigned short h) {
    unsigned u = ((unsigned)h) << 16;
    return __builtin_bit_cast(float, u);
}
__device__ inline unsigned short f2h_bits(float f) {
    __half h = __float2half_rn(f);
    return __builtin_bit_cast(unsigned short, h);
}
__device__ inline float h2f(unsigned short bits) {
    return __half2float(__builtin_bit_cast(__half, bits));
}
__device__ inline float2 h2f2(unsigned int bits) {
    __half2 h = __builtin_bit_cast(__half2, bits);
    return __half22float2(h);
}

// ---------------------------------------------------------------------------
// prep: blocks 0-7  -> W1 hi/lo bf16 frags (for split-precision gemm1)
//       blocks 8-11 -> W2 fp16 frags (for fused MFMA matvec)
//       block 12    -> zero gcur
// frag layout (16x16x32): k = kt*32 + (lane>>4)*8 + i, c = ct*16 + (lane&15)
// ---------------------------------------------------------------------------

__global__ __launch_bounds__(256) void prep_kernel(const float* __restrict__ W1,
                                                   const float* __restrict__ W2,
                                                   unsigned short* __restrict__ wh1,
                                                   unsigned short* __restrict__ wl1,
                                                   unsigned short* __restrict__ w2f,
                                                   int* __restrict__ gcur) {
    const int tid = threadIdx.x;
    const int b = blockIdx.x;
    if (b < 8) {
        constexpr int NCT = 8;  // 128/16
        int idx = b * 256 + tid;
        int lane = idx & 63;
        int rem = idx >> 6;
        int ct = rem % NCT;
        int kt = rem / NCT;
        int kbase = kt * 32 + ((lane >> 4) * 8);
        int c = ct * 16 + (lane & 15);
#pragma unroll
        for (int i = 0; i < 8; i++) {
            float v = W1[(size_t)(kbase + i) * 128 + c];
            unsigned short hi = f2bf(v);
            unsigned short lo = f2bf(v - bf2f(hi));
            wh1[(size_t)idx * 8 + i] = hi;
            wl1[(size_t)idx * 8 + i] = lo;
        }
    } else if (b < 12) {
        constexpr int NCT = 4;  // 64/16
        int idx = (b - 8) * 256 + tid;  // [0,1024)
        int lane = idx & 63;
        int rem = idx >> 6;
        int ct = rem % NCT;
        int kt = rem / NCT;
        int kbase = kt * 32 + ((lane >> 4) * 8);
        int c = ct * 16 + (lane & 15);
#pragma unroll
        for (int i = 0; i < 8; i++) {
            w2f[(size_t)idx * 8 + i] = f2h_bits(W2[(size_t)(kbase + i) * 64 + c]);
        }
    } else {
        if (tid < NBUCK) gcur[tid] = 0;
    }
}

// ---------------------------------------------------------------------------
// GEMM1 body via MFMA 16x16x32 bf16, split-precision: H = X @ W1 (fp16 out)
// ---------------------------------------------------------------------------

__device__ __forceinline__ void gemm1_body(const float* __restrict__ X,
                                           const unsigned short* __restrict__ wh,
                                           const unsigned short* __restrict__ wl,
                                           unsigned short* __restrict__ H,
                                           unsigned short* s_wh,
                                           unsigned short* s_wl,
                                           int tid, int bid) {
    constexpr int NCT = 8;

    const int wave = tid >> 6;
    const int lane = tid & 63;

    const int row0 = bid * 128 + wave * 16 + (lane & 15);
    const bool active = (bid * 128 + wave * 16) < NODES;  // wave-uniform

    float xs[4][8];
    if (active) {
        const float* xrow = X + (size_t)row0 * 128 + ((lane >> 4) * 8);
#pragma unroll
        for (int kt = 0; kt < 4; kt++) {
            float4 a = *(const float4*)(xrow + kt * 32);
            float4 b = *(const float4*)(xrow + kt * 32 + 4);
            xs[kt][0] = a.x; xs[kt][1] = a.y; xs[kt][2] = a.z; xs[kt][3] = a.w;
            xs[kt][4] = b.x; xs[kt][5] = b.y; xs[kt][6] = b.z; xs[kt][7] = b.w;
        }
    }

#pragma unroll
    for (int j = 0; j < 4; j++) {
        __builtin_amdgcn_global_load_lds((const unsigned int*)((const char*)wh + ((size_t)tid + j * 512) * 16),
                                         (unsigned int*)(s_wh + ((size_t)tid + j * 512) * 8), 16, 0, 0);
        __builtin_amdgcn_global_load_lds((const unsigned int*)((const char*)wl + ((size_t)tid + j * 512) * 16),
                                         (unsigned int*)(s_wl + ((size_t)tid + j * 512) * 8), 16, 0, 0);
    }
    __syncthreads();

    if (!active) return;

    short8 ah[4], al[4];
#pragma unroll
    for (int kt = 0; kt < 4; kt++) {
#pragma unroll
        for (int i = 0; i < 8; i++) {
            unsigned short hi = f2bf(xs[kt][i]);
            unsigned short lo = f2bf(xs[kt][i] - bf2f(hi));
            ah[kt][i] = (short)hi;
            al[kt][i] = (short)lo;
        }
    }

    f32x4 acc[NCT];
#pragma unroll
    for (int ct = 0; ct < NCT; ct++) acc[ct] = (f32x4){0.f, 0.f, 0.f, 0.f};

#pragma unroll
    for (int kt = 0; kt < 4; kt++) {
#pragma unroll
        for (int ct = 0; ct < NCT; ct++) {
            const int fo = ((kt * NCT + ct) * 64 + lane) * 8;
            short8 bh = *(const short8*)&s_wh[fo];
            short8 bl = *(const short8*)&s_wl[fo];
            acc[ct] = __builtin_amdgcn_mfma_f32_16x16x32_bf16(ah[kt], bh, acc[ct], 0, 0, 0);
            acc[ct] = __builtin_amdgcn_mfma_f32_16x16x32_bf16(al[kt], bh, acc[ct], 0, 0, 0);
            acc[ct] = __builtin_amdgcn_mfma_f32_16x16x32_bf16(ah[kt], bl, acc[ct], 0, 0, 0);
        }
    }

    // D layout: col = lane&15, row = (lane>>4)*4 + reg
    const int rbase = bid * 128 + wave * 16 + ((lane >> 4) * 4);
#pragma unroll
    for (int ct = 0; ct < NCT; ct++) {
#pragma unroll
        for (int r = 0; r < 4; r++) {
            H[(size_t)(rbase + r) * 128 + ct * 16 + (lane & 15)] = f2h_bits(acc[ct][r]);
        }
    }
}

// ---------------------------------------------------------------------------
// FUSED dispatch: blocks [0,GB) = gemm1; blocks [GB,GB+SC) = bucket_scatter
// ---------------------------------------------------------------------------

__global__ __launch_bounds__(512) void gemm1_scatter(const float* __restrict__ X,
                                                     const unsigned short* __restrict__ wh,
                                                     const unsigned short* __restrict__ wl,
                                                     unsigned short* __restrict__ H,
                                                     const int* __restrict__ erow,
                                                     const int* __restrict__ ecol,
                                                     int* __restrict__ gcur,
                                                     int2* __restrict__ temp) {
    __shared__ __align__(16) char smem[65536];
    const int tid = threadIdx.x;

    if (blockIdx.x < GB) {
        unsigned short* s_wh = (unsigned short*)smem;
        unsigned short* s_wl = s_wh + 2048 * 8;
        gemm1_body(X, wh, wl, H, s_wh, s_wl, tid, blockIdx.x);
    } else {
        int* hist = (int*)smem;
        int* rbase = hist + NBUCK;
        const int ebase = (blockIdx.x - GB) * 1024;
        if (tid < NBUCK) hist[tid] = 0;
        __syncthreads();

        const int e0 = ebase + tid;
        const int e1 = ebase + tid + 512;
        const bool v0 = e0 < EDGES;
        const bool v1 = e1 < EDGES;
        int c0 = 0, s0 = 0, b0 = 0, r0 = 0;
        int c1 = 0, s1 = 0, b1 = 0, r1 = 0;
        if (v0) {
            c0 = ecol[e0]; s0 = erow[e0];
            b0 = c0 >> BSHIFT;
            r0 = atomicAdd(&hist[b0], 1);
        }
        if (v1) {
            c1 = ecol[e1]; s1 = erow[e1];
            b1 = c1 >> BSHIFT;
            r1 = atomicAdd(&hist[b1], 1);
        }
        __syncthreads();
        if (tid < NBUCK) {
            int h = hist[tid];
            rbase[tid] = h ? atomicAdd(&gcur[tid], h) : 0;
        }
        __syncthreads();
        if (v0) {
            int2 v; v.x = s0; v.y = c0 & (BNODES - 1);
            temp[(size_t)b0 * BCAP + rbase[b0] + r0] = v;
        }
        if (v1) {
            int2 v; v.x = s1; v.y = c1 & (BNODES - 1);
            temp[(size_t)b1 * BCAP + rbase[b1] + r1] = v;
        }
    }
}

// ---------------------------------------------------------------------------
// CSR build per bucket, inline 196-wide scan
// ---------------------------------------------------------------------------

__global__ __launch_bounds__(1024) void bucket_build(const int2* __restrict__ temp,
                                                     const int* __restrict__ gcur,
                                                     int* __restrict__ row_start,
                                                     float* __restrict__ dis,
                                                     int* __restrict__ esrc) {
    __shared__ int cnt[BNODES];
    __shared__ int offs[BNODES];
    __shared__ int cur[BNODES];
    __shared__ int ssc[256];
    const int b = blockIdx.x;
    const int tid = threadIdx.x;

    if (tid < 256) ssc[tid] = (tid < NBUCK) ? gcur[tid] : 0;
    __syncthreads();
    for (int d = 1; d < 256; d <<= 1) {
        int x = (tid < 256 && tid >= d) ? ssc[tid - d] : 0;
        __syncthreads();
        if (tid < 256) ssc[tid] += x;
        __syncthreads();
    }
    const int size = gcur[b];
    const int gbase = ssc[b] - size;  // exclusive prefix
    if (b == 0 && tid == 0) row_start[NODES] = EDGES;

    if (tid < BNODES) cnt[tid] = 0;
    __syncthreads();

    for (int i = tid; i < size; i += 1024) {
        int2 v = temp[(size_t)b * BCAP + i];
        atomicAdd(&cnt[v.y], 1);
    }
    __syncthreads();

    if (tid < BNODES) offs[tid] = cnt[tid];
    __syncthreads();
    for (int d = 1; d < BNODES; d <<= 1) {
        int x = 0;
        if (tid < BNODES && tid >= d) x = offs[tid - d];
        __syncthreads();
        if (tid < BNODES) offs[tid] += x;
        __syncthreads();
    }
    if (tid < BNODES) {
        int excl = offs[tid] - cnt[tid];
        cur[tid] = excl;
        int v = b * BNODES + tid;
        if (v < NODES) {
            row_start[v] = gbase + excl;
            dis[v] = rsqrtf((float)(cnt[tid] + 1));  // +1 self-loop
        }
    }
    __syncthreads();

    for (int i = tid; i < size; i += 1024) {
        int2 v = temp[(size_t)b * BCAP + i];
        int pos = gbase + atomicAdd(&cur[v.y], 1);
        esrc[pos] = v.x;
    }
}

// ---------------------------------------------------------------------------
// FUSED agg1 + gemm2:
//   phase A: out1[v] = relu(dv*(S dis_s*h1[s] + dv*h1[v]) + b1) -> f32 LDS
//   phase B: h2[v] = out1[v] @ W2 via MFMA f16 (W2 frags staged in LDS)
// 16 nodes/block, GL=16 lanes/node; exact grid 6250 (barrier-safe, no tail).
// ---------------------------------------------------------------------------

__global__ __launch_bounds__(256, 6) void agg1_gemm2(const unsigned short* __restrict__ H,
                                                     const int* __restrict__ row_start,
                                                     const int* __restrict__ edge_src,
                                                     const float* __restrict__ dis,
                                                     const float* __restrict__ b1,
                                                     const unsigned short* __restrict__ w2f,
                                                     unsigned short* __restrict__ H2) {
    __shared__ float h_lds[16][132];            // 8.25 KB (stride 132)
    __shared__ unsigned short s_w2[1024 * 8];   // 16 KB fp16 W2 frags

    const int tid = threadIdx.x;
    const int lane = tid & 63;
    const int sub = lane & 15;
    const int grp = lane >> 4;
    const int nl = (tid >> 6) * 4 + grp;        // node_local in [0,16)
    const int v = blockIdx.x * 16 + nl;

    // stage W2 frags (16KB, linear) — latency hides under the gather phase
#pragma unroll
    for (int j = 0; j < 4; j++) {
        __builtin_amdgcn_global_load_lds((const unsigned int*)((const char*)w2f + ((size_t)tid + j * 256) * 16),
                                         (unsigned int*)(s_w2 + ((size_t)tid + j * 256) * 8), 16, 0, 0);
    }

    // ---- phase A: dis-weighted gather ----
    const uint4* __restrict__ Hq = (const uint4*)H;
    const int e0 = row_start[v];
    const int e1 = row_start[v + 1];
    const float dv = dis[v];

    const float4 ba = ((const float4*)b1)[sub * 2];
    const float4 bb = ((const float4*)b1)[sub * 2 + 1];

    uint4 gs = Hq[(size_t)v * 16 + sub];  // self row

    int i0 = edge_src[min(e0 + 0, EDGES - 1)];
    int i1 = edge_src[min(e0 + 1, EDGES - 1)];
    int i2 = edge_src[min(e0 + 2, EDGES - 1)];
    int i3 = edge_src[min(e0 + 3, EDGES - 1)];
    float d0 = dis[i0], d1 = dis[i1], d2 = dis[i2], d3 = dis[i3];

    float a0, a1, a2, a3, a4, a5, a6, a7;
    {
        float2 f0 = h2f2(gs.x), f1 = h2f2(gs.y), f2 = h2f2(gs.z), f3 = h2f2(gs.w);
        a0 = f0.x * dv; a1 = f0.y * dv; a2 = f1.x * dv; a3 = f1.y * dv;
        a4 = f2.x * dv; a5 = f2.y * dv; a6 = f3.x * dv; a7 = f3.y * dv;
    }

    for (int k = e0; k < e1; k += 4) {
        uint4 g0 = Hq[(size_t)i0 * 16 + sub];
        uint4 g1 = Hq[(size_t)i1 * 16 + sub];
        uint4 g2 = Hq[(size_t)i2 * 16 + sub];
        uint4 g3 = Hq[(size_t)i3 * 16 + sub];
        const int n0 = edge_src[min(k + 4, EDGES - 1)];
        const int n1 = edge_src[min(k + 5, EDGES - 1)];
        const int n2 = edge_src[min(k + 6, EDGES - 1)];
        const int n3 = edge_src[min(k + 7, EDGES - 1)];
        const float dn0 = dis[n0], dn1 = dis[n1], dn2 = dis[n2], dn3 = dis[n3];
        const float w0 = d0;
        const float w1 = (k + 1 < e1) ? d1 : 0.f;
        const float w2 = (k + 2 < e1) ? d2 : 0.f;
        const float w3 = (k + 3 < e1) ? d3 : 0.f;
#define ACC(G, W)                                                        \
        {                                                                \
            float2 f0 = h2f2(G.x), f1 = h2f2(G.y);                       \
            float2 f2 = h2f2(G.z), f3 = h2f2(G.w);                       \
            a0 = fmaf(f0.x, W, a0); a1 = fmaf(f0.y, W, a1);              \
            a2 = fmaf(f1.x, W, a2); a3 = fmaf(f1.y, W, a3);              \
            a4 = fmaf(f2.x, W, a4); a5 = fmaf(f2.y, W, a5);              \
            a6 = fmaf(f3.x, W, a6); a7 = fmaf(f3.y, W, a7);              \
        }
        ACC(g0, w0)
        ACC(g1, w1)
        ACC(g2, w2)
        ACC(g3, w3)
#undef ACC
        i0 = n0; i1 = n1; i2 = n2; i3 = n3;
        d0 = dn0; d1 = dn1; d2 = dn2; d3 = dn3;
    }

    // out1 epilogue -> LDS (f32, full precision, relu'd)
    {
        float4 oa, ob;
        oa.x = fmaxf(fmaf(a0, dv, ba.x), 0.f);
        oa.y = fmaxf(fmaf(a1, dv, ba.y), 0.f);
        oa.z = fmaxf(fmaf(a2, dv, ba.z), 0.f);
        oa.w = fmaxf(fmaf(a3, dv, ba.w), 0.f);
        ob.x = fmaxf(fmaf(a4, dv, bb.x), 0.f);
        ob.y = fmaxf(fmaf(a5, dv, bb.y), 0.f);
        ob.z = fmaxf(fmaf(a6, dv, bb.z), 0.f);
        ob.w = fmaxf(fmaf(a7, dv, bb.w), 0.f);
        *(float4*)&h_lds[nl][sub * 8] = oa;
        *(float4*)&h_lds[nl][sub * 8 + 4] = ob;
    }
    __syncthreads();  // h_lds ready + W2 frags staged (vmcnt drained)

    // ---- phase B: MFMA f16 matvec, wave ct = wave id, 4 MFMA ----
    const int ct = tid >> 6;
    f32x4 acc = (f32x4){0.f, 0.f, 0.f, 0.f};
#pragma unroll
    for (int kt = 0; kt < 4; kt++) {
        const int arow = lane & 15;
        const int acol = (lane >> 4) * 8 + kt * 32;
        float4 pa = *(const float4*)&h_lds[arow][acol];
        float4 pb = *(const float4*)&h_lds[arow][acol + 4];
        half8 af;
        af[0] = (_Float16)pa.x; af[1] = (_Float16)pa.y;
        af[2] = (_Float16)pa.z; af[3] = (_Float16)pa.w;
        af[4] = (_Float16)pb.x; af[5] = (_Float16)pb.y;
        af[6] = (_Float16)pb.z; af[7] = (_Float16)pb.w;
        half8 bf = *(const half8*)&s_w2[((kt * 4 + ct) * 64 + lane) * 8];
        acc = __builtin_amdgcn_mfma_f32_16x16x32_f16(af, bf, acc, 0, 0, 0);
    }

    // D layout: col = lane&15 (out ch ct*16+col), row = (lane>>4)*4 + reg (node)
    const int rbase = blockIdx.x * 16 + ((lane >> 4) * 4);
#pragma unroll
    for (int r = 0; r < 4; r++) {
        H2[(size_t)(rbase + r) * 64 + ct * 16 + (lane & 15)] = f2h_bits(acc[r]);
    }
}

// ---------------------------------------------------------------------------
// Aggregation layer 2 (64ch fp16 in, f32 out), dis-weighted edges
// ---------------------------------------------------------------------------

__global__ __launch_bounds__(256, 8) void agg_l2(const unsigned short* __restrict__ H,
                                                 const int* __restrict__ row_start,
                                                 const int* __restrict__ edge_src,
                                                 const float* __restrict__ dis,
                                                 const float* __restrict__ bias,
                                                 float* __restrict__ OUT) {
    constexpr int RQ = 8;  // row length in uint4

    const int lane = threadIdx.x & 63;
    const int sub = lane & 7;
    const int grp = lane >> 3;
    const int wid = (blockIdx.x * 256 + threadIdx.x) >> 6;
    const int v = wid * 8 + grp;

    const uint4* __restrict__ Hq = (const uint4*)H;

    const int e0 = row_start[v];
    const int e1 = row_start[v + 1];
    const float dv = dis[v];

    const float4 ba = ((const float4*)bias)[sub * 2];
    const float4 bb = ((const float4*)bias)[sub * 2 + 1];

    uint4 gs = Hq[(size_t)v * RQ + sub];

    int i0 = edge_src[min(e0 + 0, EDGES - 1)];
    int i1 = edge_src[min(e0 + 1, EDGES - 1)];
    int i2 = edge_src[min(e0 + 2, EDGES - 1)];
    int i3 = edge_src[min(e0 + 3, EDGES - 1)];
    float d0 = dis[i0], d1 = dis[i1], d2 = dis[i2], d3 = dis[i3];

    float a0, a1, a2, a3, a4, a5, a6, a7;
    {
        float2 f0 = h2f2(gs.x), f1 = h2f2(gs.y), f2 = h2f2(gs.z), f3 = h2f2(gs.w);
        a0 = f0.x * dv; a1 = f0.y * dv; a2 = f1.x * dv; a3 = f1.y * dv;
        a4 = f2.x * dv; a5 = f2.y * dv; a6 = f3.x * dv; a7 = f3.y * dv;
    }

    for (int k = e0; k < e1; k += 4) {
        uint4 g0 = Hq[(size_t)i0 * RQ + sub];
        uint4 g1 = Hq[(size_t)i1 * RQ + sub];
        uint4 g2 = Hq[(size_t)i2 * RQ + sub];
        uint4 g3 = Hq[(size_t)i3 * RQ + sub];
        const int n0 = edge_src[min(k + 4, EDGES - 1)];
        const int n1 = edge_src[min(k + 5, EDGES - 1)];
        const int n2 = edge_src[min(k + 6, EDGES - 1)];
        const int n3 = edge_src[min(k + 7, EDGES - 1)];
        const float dn0 = dis[n0], dn1 = dis[n1], dn2 = dis[n2], dn3 = dis[n3];
        const float w0 = d0;
        const float w1 = (k + 1 < e1) ? d1 : 0.f;
        const float w2 = (k + 2 < e1) ? d2 : 0.f;
        const float w3 = (k + 3 < e1) ? d3 : 0.f;
#define ACC(G, W)                                                        \
        {                                                                \
            float2 f0 = h2f2(G.x), f1 = h2f2(G.y);                       \
            float2 f2 = h2f2(G.z), f3 = h2f2(G.w);                       \
            a0 = fmaf(f0.x, W, a0); a1 = fmaf(f0.y, W, a1);              \
            a2 = fmaf(f1.x, W, a2); a3 = fmaf(f1.y, W, a3);              \
            a4 = fmaf(f2.x, W, a4); a5 = fmaf(f2.y, W, a5);              \
            a6 = fmaf(f3.x, W, a6); a7 = fmaf(f3.y, W, a7);              \
        }
        ACC(g0, w0)
        ACC(g1, w1)
        ACC(g2, w2)
        ACC(g3, w3)
#undef ACC
        i0 = n0; i1 = n1; i2 = n2; i3 = n3;
        d0 = dn0; d1 = dn1; d2 = dn2; d3 = dn3;
    }

    float4 oa, ob;
    oa.x = fmaf(a0, dv, ba.x); oa.y = fmaf(a1, dv, ba.y);
    oa.z = fmaf(a2, dv, ba.z); oa.w = fmaf(a3, dv, ba.w);
    ob.x = fmaf(a4, dv, bb.x); ob.y = fmaf(a5, dv, bb.y);
    ob.z = fmaf(a6, dv, bb.z); ob.w = fmaf(a7, dv, bb.w);
    float* outp = OUT + (size_t)v * 64 + sub * 8;
    *(float4*)(outp) = oa;
    *(float4*)(outp + 4) = ob;
}

// ---------------------------------------------------------------------------

extern "C" void kernel_launch(void* const* d_in, const int* in_sizes, int n_in,
                              void* d_out, int out_size, void* d_ws, size_t ws_size,
                              hipStream_t stream) {
    const float* x   = (const float*)d_in[0];
    const int* eidx  = (const int*)d_in[1];
    const float* W1  = (const float*)d_in[2];
    const float* b1  = (const float*)d_in[3];
    const float* W2  = (const float*)d_in[4];
    const float* b2  = (const float*)d_in[5];
    float* out = (float*)d_out;

    const int* erow = eidx;          // sources
    const int* ecol = eidx + EDGES;  // targets

    // workspace carve-up (256B aligned)
    char* w = (char*)d_ws;
    size_t off = 0;
    auto alloc = [&](size_t bytes) -> void* {
        void* p = w + off;
        off += (bytes + 255) & ~(size_t)255;
        return p;
    };
    float* dis     = (float*)alloc((size_t)NODES * 4);
    int*   rowst   = (int*)alloc((size_t)(NODES + 1) * 4);
    int*   esrc    = (int*)alloc((size_t)EDGES * 4);
    int*   gcur    = (int*)alloc(NBUCK * 4);
    int2*  temp    = (int2*)alloc((size_t)NBUCK * BCAP * 8);
    unsigned short* wh1 = (unsigned short*)alloc(2048 * 8 * 2);
    unsigned short* wl1 = (unsigned short*)alloc(2048 * 8 * 2);
    unsigned short* w2f = (unsigned short*)alloc(1024 * 8 * 2);
    unsigned short* bufA = (unsigned short*)alloc((size_t)NODES * 128 * 2);  // h1 (fp16)
    unsigned short* bufC = (unsigned short*)alloc((size_t)NODES * 64 * 2);   // h2 (fp16)

    // 1) weight prep + gcur zero
    prep_kernel<<<13, 256, 0, stream>>>(W1, W2, wh1, wl1, w2f, gcur);

    // 2) FUSED: gemm1 (h1 = x@W1, fp16) || bucket_scatter
    gemm1_scatter<<<GB + SC, 512, 0, stream>>>(x, wh1, wl1, bufA, erow, ecol, gcur, temp);

    // 3) CSR build (row_start, dis, esrc)
    bucket_build<<<NBUCK, 1024, 0, stream>>>(temp, gcur, rowst, dis, esrc);

    // 4) FUSED agg1 + gemm2: h2 = relu(dis*(S dis_s h1) + b1) @ W2  (fp16)
    agg1_gemm2<<<NODES / 16, 256, 0, stream>>>(bufA, rowst, esrc, dis, b1, w2f, bufC);

    // 5) agg2: out = dis*(S dis_s h2 + dis_v h2[v]) + b2  (f32)
    agg_l2<<<NODES / 32, 256, 0, stream>>>(bufC, rowst, esrc, dis, b2, out);
}